// Round 9
// baseline (224.730 us; speedup 1.0000x reference)
//
#include <hip/hip_runtime.h>
#include <hip/hip_bf16.h>
#include <stdint.h>

#define NUM_MODALS 4
#define SHARED_IDX 3

typedef __attribute__((ext_vector_type(8))) short bf16x8;
typedef __attribute__((ext_vector_type(4))) float floatx4;

__device__ __forceinline__ unsigned short f2bf(float f) {
  unsigned int u = __float_as_uint(f);
  u += 0x7fffu + ((u >> 16) & 1u);   // round-to-nearest-even
  return (unsigned short)(u >> 16);
}

// ---------------- W_eff build (round-0 proven version) ----------------
// W_eff[m][o][c] = Wp[o][c] + sum_r Bw[3][o][r]*A[3][r][c] + sum_r Bw[m][o][r]*A[m][r][c]
__global__ __launch_bounds__(256) void weff_fast(
    const float* __restrict__ Wp, const float* __restrict__ A,
    const float* __restrict__ Bw, unsigned short* __restrict__ Weff) {
  const int c  = blockIdx.x * 256 + threadIdx.x;
  const int o0 = blockIdx.y * 16;
  const int m  = blockIdx.z;

  __shared__ float b3[256], bm[256];   // 16 o-rows x 16 r, both adapters
  const int t = threadIdx.x;
  {
    const int o = o0 + (t >> 4);
    const int r = t & 15;
    b3[t] = Bw[(SHARED_IDX * 768 + o) * 16 + r];
    bm[t] = Bw[((size_t)m * 768 + o) * 16 + r];
  }
  __syncthreads();

  float a3[16], am[16];
#pragma unroll
  for (int r = 0; r < 16; ++r) {
    a3[r] = A[(SHARED_IDX * 16 + r) * 768 + c];
    am[r] = A[((size_t)m * 16 + r) * 768 + c];
  }
#pragma unroll 4
  for (int oo = 0; oo < 16; ++oo) {
    const int o = o0 + oo;
    float acc = Wp[(size_t)o * 768 + c];
#pragma unroll
    for (int r = 0; r < 16; ++r) {
      acc += b3[oo * 16 + r] * a3[r];
      acc += bm[oo * 16 + r] * am[r];
    }
    Weff[((size_t)m * 768 + o) * 768 + c] = f2bf(acc);
  }
}

// ---------------- fused GEMM: out[m] = X[m] (fp32, cvt in-reg) * Weff[m]^T + bp ----
// Round-9: GRID REBALANCE on the round-8 skeleton. Tile 128x192 (BN 256->192),
// grid 1024 = exactly 4 blocks/CU with 2 resident -> balanced 2+2 execution,
// eliminating round-8's solo-block tail (768 blocks / 512 slots = 1.5 waves;
// OccupancyPercent 31% avg vs 50% ceiling showed the machine ran the last
// third at half throughput). Staged bytes/MFMA 250->208 (40 KB per kt for
// 192 MFMAs). Registers SHRINK vs r8 (acc 4x3=48 AGPR + ~64 arch ~= 112 <=
// 128) -> 4 waves/SIMD with headroom (r8 sat exactly at the 128 cliff).
// LDS = As 16 KB + Ws dbuf 2x192x64x2 = 48 KB -> 64 KB total, 2 blocks/CU.
// Pipeline identical to r3/r8: counted-vmcnt raw-barrier, X distance 1,
// W distance 2 via Ws dbuf; setprio around MFMA cluster.
// vmcnt ledger (per wave): prologue W(0):3, X(0):4, W(1):3 -> queue 10.
// Top of kt: [W(kt):3, X(kt):4, W(kt+1):3] -> vmcnt(3) retires {W(kt),X(kt)}.
// Mid-kt: issue X(kt+1):4 (kt<11). After bar-2: issue W(kt+2):3 (kt<10).
// kt=11: queue [W11:3, X11:4] -> vmcnt(0). Issues: X 1+11=12, W 2+10=12.
// Hazards: Ws[b] re-staged only after bar-2 of the kt that read it; As written
// at kt-top ordered after bar-2 of kt-1; all s_barriers unconditional.
// XCD remap: 1024 % 8 == 0 -> bijective; 128 blocks/XCD; ct = w%4 varies
// fastest so the 4 col-tiles of a row-tile are adjacent (X row-tile L2 reuse);
// 2 XCDs per modality -> Weff[m] (1.2 MB bf16) L2-resident.
__global__ void lora_gemm_fused(
    const float* __restrict__ X,
    const unsigned short* __restrict__ Weff,
    const float* __restrict__ bp,
    float* __restrict__ out) {
  const int bid = blockIdx.x;
  const int xcd = bid & 7;
  const int s   = bid >> 3;          // 0..127
  const int w   = xcd * 128 + s;     // contiguous per-XCD chunk
  const int ct  = w & 3;             // 4 col-tiles of 192
  const int rt  = w >> 2;            // 0..255 row-tiles of 128
  const int m        = rt >> 6;      // 64 row-tiles per modality
  const int row_base = (rt & 63) * 128;
  const int col_base = ct * 192;

  __shared__ alignas(16) unsigned short As[128 * 64];       // 16 KB
  __shared__ alignas(16) unsigned short Ws[2 * 192 * 64];   // 48 KB (dbuf)

  const int tid  = threadIdx.x;      // 0..511
  const int wave = tid >> 6;         // 0..7
  const int lane = tid & 63;
  const int ln = lane & 15;
  const int qd = lane >> 4;
  const int wm = wave & 1;           // M half (2 x 64 rows)
  const int wn = wave >> 1;          // N quadrant (4 x 48 cols)

  const float*          Xm = X    + (size_t)m * 8192 * 768;
  const unsigned short* Wm = Weff + (size_t)m * 768 * 768;

  floatx4 acc[4][3];
#pragma unroll
  for (int i = 0; i < 4; ++i)
#pragma unroll
    for (int j = 0; j < 3; ++j)
      acc[i][j] = (floatx4)(0.0f);

  // --- X staging: thread covers (row xr+p*32, 4 fp32 cols at xc), p=0..3 ---
  const int xr   = tid >> 4;         // 0..31
  const int xc   = (tid & 15) * 4;   // 0..60
  const int cb   = xc >> 3;          // 16B col-block 0..7
  const int half = (xc >> 2) & 1;    // which 8B half of the block
  const float* xsrc[4];
  unsigned short* xdst[4];
#pragma unroll
  for (int p = 0; p < 4; ++p) {
    const int r = xr + p * 32;       // 0..127
    xsrc[p] = Xm + (size_t)(row_base + r) * 768 + xc;
    xdst[p] = &As[r * 64 + (cb ^ (r & 7)) * 8 + half * 4];
  }
  // --- W staging (global_load_lds w16: one issue = 8 rows x 128 B per wave) ---
  const int sr = lane >> 3;          // row-in-8
  const int ss = lane & 7;           // LDS slot this lane fills
  const unsigned short* wsrc[3];
#pragma unroll
  for (int p = 0; p < 3; ++p) {
    const int r = wave * 24 + p * 8 + sr;   // 0..191
    wsrc[p] = Wm + (size_t)(col_base + r) * 768 + (ss ^ (r & 7)) * 8;
  }

  // ---- prologue: issue W(0)->Ws[0], X(0)->xv, W(1)->Ws[1] ----
  float4 xv[4];
#pragma unroll
  for (int p = 0; p < 3; ++p) {
    __builtin_amdgcn_global_load_lds(
        (const __attribute__((address_space(1))) void*)wsrc[p],
        (__attribute__((address_space(3))) void*)&Ws[(wave * 24 + p * 8) * 64],
        16, 0, 0);
    wsrc[p] += 64;
  }
#pragma unroll
  for (int p = 0; p < 4; ++p) {
    xv[p] = *(const float4*)xsrc[p];
    xsrc[p] += 64;
  }
#pragma unroll
  for (int p = 0; p < 3; ++p) {
    __builtin_amdgcn_global_load_lds(
        (const __attribute__((address_space(1))) void*)wsrc[p],
        (__attribute__((address_space(3))) void*)&Ws[192 * 64 + (wave * 24 + p * 8) * 64],
        16, 0, 0);
    wsrc[p] += 64;
  }

  for (int kt = 0; kt < 12; ++kt) {
    const int boff = (kt & 1) * (192 * 64);

    // retire W(kt) + X(kt); keep W(kt+1) in flight across the barrier (T4)
    if (kt < 11) {
      asm volatile("s_waitcnt vmcnt(3)" ::: "memory");
    } else {
      asm volatile("s_waitcnt vmcnt(0)" ::: "memory");
    }

    // convert + write X(kt) into As (loads issued a full phase ago)
#pragma unroll
    for (int p = 0; p < 4; ++p) {
      const float4 v = xv[p];
      __hip_bfloat162 h0 = __float22bfloat162_rn(make_float2(v.x, v.y));
      __hip_bfloat162 h1 = __float22bfloat162_rn(make_float2(v.z, v.w));
      uint2 hv;
      hv.x = *(unsigned int*)&h0;
      hv.y = *(unsigned int*)&h1;
      *(uint2*)xdst[p] = hv;
    }

    // issue X(kt+1) -> regs (consumed at top of kt+1, hidden under compute)
    if (kt < 11) {
#pragma unroll
      for (int p = 0; p < 4; ++p) {
        xv[p] = *(const float4*)xsrc[p];
        xsrc[p] += 64;
      }
    }

    // barrier 1: As writes visible (lgkm drained), Ws[b] globally valid
    asm volatile("s_waitcnt lgkmcnt(0)" ::: "memory");
    __builtin_amdgcn_sched_barrier(0);
    __builtin_amdgcn_s_barrier();
    __builtin_amdgcn_sched_barrier(0);

    // compute(kt) on As / Ws[b]
    __builtin_amdgcn_s_setprio(1);
#pragma unroll
    for (int kk = 0; kk < 64; kk += 32) {
      const int kblk = (kk >> 3) + qd;           // 0..7
      const int slot = (kblk ^ (ln & 7)) * 8;
      bf16x8 a[4], b[3];
#pragma unroll
      for (int i = 0; i < 4; ++i)
        a[i] = *(const bf16x8*)(&As[(wm * 64 + i * 16 + ln) * 64 + slot]);
#pragma unroll
      for (int j = 0; j < 3; ++j)
        b[j] = *(const bf16x8*)(&Ws[boff + (wn * 48 + j * 16 + ln) * 64 + slot]);
#pragma unroll
      for (int i = 0; i < 4; ++i)
#pragma unroll
        for (int j = 0; j < 3; ++j)
          acc[i][j] = __builtin_amdgcn_mfma_f32_16x16x32_bf16(a[i], b[j], acc[i][j], 0, 0, 0);
    }
    __builtin_amdgcn_s_setprio(0);

    // barrier 2: every wave done reading Ws[b] / As -> safe to re-stage
    __builtin_amdgcn_sched_barrier(0);
    __builtin_amdgcn_s_barrier();
    __builtin_amdgcn_sched_barrier(0);

    // issue W(kt+2) -> Ws[b] (buffer compute(kt) just vacated); in flight
    // through all of iter kt+1, waited at top of iter kt+2.
    if (kt < 10) {
#pragma unroll
      for (int p = 0; p < 3; ++p) {
        __builtin_amdgcn_global_load_lds(
            (const __attribute__((address_space(1))) void*)wsrc[p],
            (__attribute__((address_space(3))) void*)&Ws[boff + (wave * 24 + p * 8) * 64],
            16, 0, 0);
        wsrc[p] += 64;
      }
    }
  }

  float* Om = out + (size_t)m * 8192 * 768;
#pragma unroll
  for (int j = 0; j < 3; ++j) {
    const int o = col_base + wn * 48 + j * 16 + ln;
    const float bias = bp[o];
#pragma unroll
    for (int i = 0; i < 4; ++i) {
      const int R = row_base + wm * 64 + i * 16 + qd * 4;
      float* dst = Om + (size_t)R * 768 + o;
#pragma unroll
      for (int v = 0; v < 4; ++v)
        dst[(size_t)v * 768] = acc[i][j][v] + bias;
    }
  }
}

extern "C" void kernel_launch(void* const* d_in, const int* in_sizes, int n_in,
                              void* d_out, int out_size, void* d_ws, size_t ws_size,
                              hipStream_t stream) {
  const float* x  = (const float*)d_in[0];   // [32, 1024, 768]
  const float* Wp = (const float*)d_in[1];   // [768, 768]
  const float* bp = (const float*)d_in[2];   // [768]
  const float* A  = (const float*)d_in[3];   // [4, 16, 768]
  const float* Bw = (const float*)d_in[4];   // [4, 768, 16]
  float* out = (float*)d_out;                // [32, 1024, 768]

  unsigned short* Weff = (unsigned short*)d_ws;  // [4][768][768] bf16 = 4.5 MB

  weff_fast<<<dim3(3, 48, 4), 256, 0, stream>>>(Wp, A, Bw, Weff);
  lora_gemm_fused<<<dim3(1024), 512, 0, stream>>>(x, Weff, bp, out);
}